// Round 6
// baseline (312.012 us; speedup 1.0000x reference)
//
#include <hip/hip_runtime.h>
#include <hip/hip_bf16.h>

#define B_    2
#define N_    4096
#define NV_   32768
#define HID_  128
#define XD_   128
#define YD_   128
#define ZD_   16
#define PLANE (XD_*YD_*ZD_)      // 262144
#define LOCS  (B_*PLANE)         // 524288
#define STEP  (100.0f/15.0f)
#define KS    4                  // K-split factor (k-chunk = 1024)
#define VBL   160                // v-blocks per seg (160*128 = 20480 > any count)
#define L2E   1.4426950408889634f

typedef __attribute__((ext_vector_type(8)))  short short8;
typedef __attribute__((ext_vector_type(16))) float f32x16;

__device__ __forceinline__ float anchor_s(int i) {   // log2e-scaled anchor coord
    return fmaf((float)i, STEP * L2E, -50.0f * L2E);
}
__device__ __forceinline__ float fexp2(float x) {
    float r; asm("v_exp_f32 %0, %1" : "=v"(r) : "v"(x)); return r;
}
__device__ __forceinline__ unsigned short f2bf(float x) {
    unsigned u = __float_as_uint(x);
    return (unsigned short)((u + 0x7fffu + ((u >> 16) & 1u)) >> 16);
}
__device__ __forceinline__ void gload16(const void* g, void* l) {
    __builtin_amdgcn_global_load_lds(
        (const __attribute__((address_space(1))) unsigned int*)g,
        (__attribute__((address_space(3))) unsigned int*)l, 16, 0, 0);
}

// ---------------- MLP: x = relu(in @ W1 + b1) @ W2 + b2 -> xwT bf16 [b][d][n] ----------------
__global__ __launch_bounds__(256) void mlp_kernel(
    const float* __restrict__ pos, const float* __restrict__ scl,
    const float* __restrict__ rot, const float* __restrict__ opa,
    const float* __restrict__ W1,  const float* __restrict__ b1,
    const float* __restrict__ W2,  const float* __restrict__ b2,
    unsigned short* __restrict__ xwT)
{
    int rg = threadIdx.x >> 7;
    int j  = threadIdx.x & 127;
    int r  = blockIdx.x * 2 + rg;
    __shared__ float sin_[2][11];
    __shared__ float h[2][HID_];
    if (j < 11) {
        float val;
        if (j < 3)       val = pos[r*3 + j];
        else if (j < 6)  val = scl[r*3 + (j-3)];
        else if (j < 10) val = rot[r*4 + (j-6)];
        else             val = opa[r];
        sin_[rg][j] = val;
    }
    __syncthreads();
    float a = b1[j];
    #pragma unroll
    for (int i = 0; i < 11; ++i) a = fmaf(sin_[rg][i], W1[i*HID_ + j], a);
    h[rg][j] = fmaxf(a, 0.0f);
    __syncthreads();
    float o = b2[j];
    for (int k = 0; k < HID_; ++k) o = fmaf(h[rg][k], W2[k*HID_ + j], o);
    int b = r >> 12, n = r & 4095;
    xwT[((size_t)(b*HID_ + j))*N_ + n] = f2bf(o);
}

// ------------- scatter: winner map + wave-aggregated batch buckets -------------
__global__ __launch_bounds__(256) void scatter_kernel(
    const int* __restrict__ vc, int* __restrict__ map,
    int* __restrict__ cnt, int* __restrict__ vlist)
{
    int v = blockIdx.x * 256 + threadIdx.x;
    int4 c = ((const int4*)vc)[v];
    int loc = ((c.x*XD_ + c.y)*YD_ + c.z)*ZD_ + c.w;
    atomicMax(&map[loc], v);
    int lane = threadIdx.x & 63;
    unsigned long long m1 = __ballot(c.x != 0);
    unsigned long long mymask = c.x ? m1 : ~m1;
    int leader = (int)__ffsll(mymask) - 1;
    int total  = __popcll(mymask);
    int rank   = __popcll(mymask & ((1ull << lane) - 1ull));
    int base = 0;
    if (lane == leader) base = atomicAdd(&cnt[c.x], total);
    base = __shfl(base, leader);
    vlist[c.x*NV_ + base + rank] = v;
}

// ------------- pass A: per-v (m_l2e, 1/l) single online pass, 8 lanes per v -------------
__global__ __launch_bounds__(256) void ml_kernel(
    const int* __restrict__ vc, float2* __restrict__ ml)
{
    int gid = blockIdx.x * 256 + threadIdx.x;
    int v = gid >> 3, sub = gid & 7;
    int4 c = ((const int4*)vc)[v];
    float vx = (float)c.y * L2E, vy = (float)c.z * L2E, vz = (float)c.w * L2E;
    float dz2_[16];
    #pragma unroll 16
    for (int iz = 0; iz < 16; ++iz) { float t = vz - anchor_s(iz); dz2_[iz] = t*t; }

    float m = 1e30f, l = 0.0f;
    #pragma unroll
    for (int i = 0; i < 2; ++i) {
        float dx = vx - anchor_s(sub*2 + i);
        float dx2 = dx*dx;
        for (int iy = 0; iy < 16; ++iy) {
            float dy = vy - anchor_s(iy);
            float bxy = fmaf(dy, dy, dx2);
            #pragma unroll 16
            for (int iz = 0; iz < 16; ++iz) {
                float d = sqrtf(bxy + dz2_[iz]);
                float dm = d - m;
                float e = fexp2(-fabsf(dm));
                bool nm = dm < 0.0f;
                l = nm ? fmaf(l, e, 1.0f) : (l + e);
                m = nm ? d : m;
            }
        }
    }
    #pragma unroll
    for (int off = 1; off < 8; off <<= 1) {
        float m2 = __shfl_xor(m, off);
        float l2 = __shfl_xor(l, off);
        float mn = fminf(m, m2);
        l = l * fexp2(mn - m) + l2 * fexp2(mn - m2);
        m = mn;
    }
    if (sub == 0) ml[v] = make_float2(m, 1.0f / l);
}

// ------------- pass B: partial[ks][v,:] = sum_{n in kseg} exp2(m - d(v,n)) * x[b_v,n,:] -------------
// 128v x 128d per block; 4 waves v-split; 32x32x16 MFMA; P computed directly
// in A-fragment registers (no P LDS); X^T staged via global_load_lds with
// pre-swizzled source so B-frag ds_read_b128 is bank-conflict-free.
__global__ __launch_bounds__(256) void fuse_kernel(
    const unsigned short* __restrict__ xwT, const float2* __restrict__ ml,
    const int* __restrict__ vc,   const int* __restrict__ vlist,
    const int* __restrict__ cnt,  float* __restrict__ fused_p)
{
    int bid  = blockIdx.x;
    int ks_  = bid & (KS-1);
    int rest = bid >> 2;
    int seg  = (rest >= VBL) ? 1 : 0;
    int bi   = rest - seg*VBL;
    int count = cnt[seg];
    int vbase = bi * 128;
    if (vbase >= count) return;
    int nv = min(128, count - vbase);
    int k0 = ks_ * (N_/KS);

    __shared__ __align__(16) unsigned char sXT[16384];  // [128 d][8 blk16], blk ^= (d&7)
    __shared__ int svid[128];

    int tid = threadIdx.x;
    int w  = tid >> 6, l = tid & 63;
    int h  = l >> 5;          // k-half within fragment
    int cl = l & 31;          // col / v-within-wave

    if (tid < 128) svid[tid] = (tid < nv) ? vlist[seg*NV_ + vbase + tid] : -1;

    // per-thread v (A-operand row)
    int vloc = w*32 + cl;
    float pml = -1e30f, pvx = 0.f, pvy = 0.f;
    float dz2_[16];
    #pragma unroll 16
    for (int iz = 0; iz < 16; ++iz) dz2_[iz] = 0.f;
    if (vloc < nv) {
        int vid = vlist[seg*NV_ + vbase + vloc];
        int4 c = ((const int4*)vc)[vid];
        pvx = (float)c.y * L2E; pvy = (float)c.z * L2E;
        float pvz = (float)c.w * L2E;
        pml = ml[vid].x;
        #pragma unroll 16
        for (int iz = 0; iz < 16; ++iz) { float t = pvz - anchor_s(iz); dz2_[iz] = t*t; }
    }

    // staging source precompute: instr i covers d = w*32 + i*8 + (l>>3), blk = l&7
    int d0s  = w*32 + (l >> 3);
    int blkX = (l & 7) ^ ((l >> 3) & 7);
    const unsigned short* sb = xwT + (size_t)(seg*128 + d0s)*N_ + blkX*8 + k0;
    char* ldsb = (char*)sXT + (size_t)(w*4)*1024;   // wave-uniform; HW adds lane*16

    f32x16 acc[4];
    #pragma unroll
    for (int i = 0; i < 4; ++i) acc[i] = (f32x16)(0.f);

    for (int t = 0; t < (N_/KS)/64; ++t) {
        __syncthreads();                       // prev tile fully consumed
        // ---- issue DMA staging of this tile ----
        #pragma unroll
        for (int i = 0; i < 4; ++i)
            gload16(sb + (size_t)i*8*N_ + t*64, ldsb + i*1024);

        // ---- compute P directly in A-fragment registers (hides DMA) ----
        unsigned pk_[4][4];
        int nb = k0 + t*64;
        #pragma unroll
        for (int kss = 0; kss < 4; ++kss) {
            int kg = nb + kss*16;
            float ax = anchor_s(kg >> 8);
            float ay = anchor_s((kg >> 4) & 15);
            float dx = pvx - ax, dy = pvy - ay;
            float bxy = fmaf(dx, dx, dy*dy);
            #pragma unroll
            for (int jj = 0; jj < 4; ++jj) {
                float dA = sqrtf(bxy + dz2_[h*8 + 2*jj]);
                float dB = sqrtf(bxy + dz2_[h*8 + 2*jj + 1]);
                float p0 = fexp2(pml - dA);
                float p1 = fexp2(pml - dB);
                asm("v_cvt_pk_bf16_f32 %0, %1, %2" : "=v"(pk_[kss][jj]) : "v"(p0), "v"(p1));
            }
        }
        __syncthreads();                       // DMA complete (vmcnt) + all waves staged

        // ---- MFMA: 4 kss x 4 d-tiles ----
        #pragma unroll
        for (int kss = 0; kss < 4; ++kss) {
            union { uint4 q; short8 s; } u8;
            u8.q = make_uint4(pk_[kss][0], pk_[kss][1], pk_[kss][2], pk_[kss][3]);
            short8 af = u8.s;
            #pragma unroll
            for (int df = 0; df < 4; ++df) {
                int row = df*32 + cl;
                int blk = (kss*2 + h) ^ (row & 7);
                short8 bf = *(const short8*)&sXT[row*128 + blk*16];
                acc[df] = __builtin_amdgcn_mfma_f32_32x32x16_bf16(af, bf, acc[df], 0, 0, 0);
            }
        }
    }

    // ---- epilogue: plain f32 stores to this kseg's partial buffer ----
    // C layout (32x32): col = lane&31, row = (reg&3) + 8*(reg>>2) + 4*(lane>>5)
    float* fp = fused_p + (size_t)ks_ * NV_ * HID_;
    #pragma unroll
    for (int df = 0; df < 4; ++df) {
        int dcol = df*32 + cl;
        #pragma unroll
        for (int reg = 0; reg < 16; ++reg) {
            int vrow = w*32 + (reg & 3) + 8*(reg >> 2) + 4*h;
            int sv = svid[vrow];
            if (sv >= 0) fp[(size_t)sv*HID_ + dcol] = acc[df][reg];
        }
    }
}

// ------------- output: sum KS partials, scale by 1/l, full-coverage coalesced write -------------
__global__ __launch_bounds__(256) void out_kernel(
    const int* __restrict__ map, const float* __restrict__ fused_p,
    const float2* __restrict__ ml, float* __restrict__ out)
{
    int q = blockIdx.x * 256 + threadIdx.x;     // quad id over LOCS/4
    int loc0 = q << 2;
    int b   = loc0 >> 18;
    int rem = loc0 & (PLANE - 1);
    int4 vv = ((const int4*)map)[q];
    size_t obase = ((size_t)b * HID_) * PLANE + rem;
    const size_t S4 = (size_t)NV_ * HID_ / 4;   // float4 stride between ks buffers
    const float4* P = (const float4*)fused_p;

    int   va[4] = {vv.x, vv.y, vv.z, vv.w};
    float il[4];
    const float4* rp[4];
    #pragma unroll
    for (int k = 0; k < 4; ++k) {
        il[k] = (va[k] >= 0) ? ml[va[k]].y : 0.0f;
        rp[k] = P + (size_t)(va[k] >= 0 ? va[k] : 0) * 32;
    }

    for (int chb = 0; chb < 32; ++chb) {
        float4 vals[4];
        #pragma unroll
        for (int k = 0; k < 4; ++k) {
            float4 s = make_float4(0.f, 0.f, 0.f, 0.f);
            if (va[k] >= 0) {
                float4 a = rp[k][chb];
                float4 bq = rp[k][chb + S4];
                float4 cq = rp[k][chb + 2*S4];
                float4 dq = rp[k][chb + 3*S4];
                s.x = (a.x + bq.x + cq.x + dq.x) * il[k];
                s.y = (a.y + bq.y + cq.y + dq.y) * il[k];
                s.z = (a.z + bq.z + cq.z + dq.z) * il[k];
                s.w = (a.w + bq.w + cq.w + dq.w) * il[k];
            }
            vals[k] = s;
        }
        *(float4*)&out[obase + (size_t)(chb*4 + 0) * PLANE] = make_float4(vals[0].x, vals[1].x, vals[2].x, vals[3].x);
        *(float4*)&out[obase + (size_t)(chb*4 + 1) * PLANE] = make_float4(vals[0].y, vals[1].y, vals[2].y, vals[3].y);
        *(float4*)&out[obase + (size_t)(chb*4 + 2) * PLANE] = make_float4(vals[0].z, vals[1].z, vals[2].z, vals[3].z);
        *(float4*)&out[obase + (size_t)(chb*4 + 3) * PLANE] = make_float4(vals[0].w, vals[1].w, vals[2].w, vals[3].w);
    }
}

extern "C" void kernel_launch(void* const* d_in, const int* in_sizes, int n_in,
                              void* d_out, int out_size, void* d_ws, size_t ws_size,
                              hipStream_t stream) {
    const float* pos = (const float*)d_in[0];
    const float* scl = (const float*)d_in[1];
    const float* rot = (const float*)d_in[2];
    const float* opa = (const float*)d_in[3];
    const float* W1  = (const float*)d_in[4];
    const float* b1  = (const float*)d_in[5];
    const float* W2  = (const float*)d_in[6];
    const float* b2  = (const float*)d_in[7];
    const int*   vc  = (const int*)d_in[8];
    float* out = (float*)d_out;

    char* ws = (char*)d_ws;
    unsigned short* xwT = (unsigned short*)(ws);        // 2 MB: bf16 x^T [b][128][4096]
    float2* ml      = (float2*)(ws + (2u<<20));         // 256 KB
    float*  fused_p = (float*) (ws + (4u<<20));         // 64 MB: KS partial buffers
    int*    map     = (int*)   (ws + (72u<<20));        // 2 MB
    int*    vlist   = (int*)   (ws + (74u<<20));        // 256 KB
    int*    cnt     = (int*)   (ws + (75u<<20));        // 8 B

    hipMemsetAsync(map, 0xFF, LOCS*sizeof(int), stream);
    hipMemsetAsync(cnt, 0, 2*sizeof(int), stream);

    mlp_kernel<<<(B_*N_)/2, 256, 0, stream>>>(pos, scl, rot, opa, W1, b1, W2, b2, xwT);
    scatter_kernel<<<NV_/256, 256, 0, stream>>>(vc, map, cnt, vlist);
    ml_kernel<<<(NV_*8)/256, 256, 0, stream>>>(vc, ml);
    fuse_kernel<<<2*VBL*KS, 256, 0, stream>>>(xwT, ml, vc, vlist, cnt, fused_p);
    out_kernel<<<LOCS/(256*4), 256, 0, stream>>>(map, fused_p, ml, out);
}